// Round 6
// baseline (1907.093 us; speedup 1.0000x reference)
//
#include <hip/hip_runtime.h>

// EdgeConv: B=32, N=2048, D=16, PCD=2, K_NN=16, FILTERS=64
// out[b,n,0:64]  = max(y_n, max_k y_{nn_k} - y_n) + b   where y = x@W (linearity)
// out[b,n,64:80] = x[b,n,:]
//
// KNN = ROUND-3 SOURCE VERBATIM (the only config that matched the np
// reference: absmax 0.031 = bf16 grid noise), with exactly ONE change:
// the 16-slot best arrays live in LDS[slot][tid] instead of scratch
// (r3 spilled: VGPR_Count=40, ~1494 cyc/iter, 1275 us).
// r4/r5's restructured selection (cndmask chains / float4 staging) failed
// identically (0.453) for reasons not yet modeled -> do not reuse ANY of it.
//
// Distance arithmetic (np-matching, verified r3):
//   sq  = fl(fl(x*x) + fl(y*y))          (no FMA)
//   dot = fma(y_n, y_m, fl(x_n*x_m))     (contracted k-loop)
//   d   = fl(fl(sq_n+sq_m) - fl(2*dot))
// Selection: unsorted 16 best, strict d<worst gate (boundary tie keeps
// incumbent = lower index), evict lexicographic-(d,idx) max.

#define B_  32
#define N_  2048
#define D_  16
#define F_  64
#define K_  16
#define OUTD (F_ + D_)   // 80

// ---------------- K1: Y = X * W  (bias folded into pool kernel) -------------
__global__ __launch_bounds__(256) void proj_kernel(const float* __restrict__ x,
                                                   const float* __restrict__ W,
                                                   float* __restrict__ Y) {
    __shared__ float Ws[D_ * F_];     // 4 KB
    __shared__ float xs[4][D_];
    const int t = threadIdx.x;
    for (int i = t; i < D_ * F_; i += 256) Ws[i] = W[i];
    const int p0 = blockIdx.x * 4;
    if (t < 4 * D_) {
        int pw = t / D_, d = t % D_;
        xs[pw][d] = x[(size_t)(p0 + pw) * D_ + d];
    }
    __syncthreads();
    const int w = t >> 6, f = t & 63;
    float acc = 0.f;
#pragma unroll
    for (int d = 0; d < D_; d++) acc = fmaf(xs[w][d], Ws[d * F_ + f], acc);
    Y[(size_t)(p0 + w) * F_ + f] = acc;
}

// ---------------- K2: exact 16-NN per point (round-3 semantics) -------------
__global__ __launch_bounds__(256) void knn_kernel(const float* __restrict__ x,
                                                  int* __restrict__ idx) {
    __shared__ float2 pts[N_];        // 16 KB
    __shared__ float  sqs[N_];        // 8 KB
    __shared__ float  bdL[K_][256];   // 16 KB  per-thread slot column t
    __shared__ int    biL[K_][256];   // 16 KB
    const int b = blockIdx.x >> 3;          // 8 blocks per batch
    const int qbase = (blockIdx.x & 7) * 256;
    const int t = threadIdx.x;
    const float* xb = x + (size_t)b * N_ * D_;
    for (int m = t; m < N_; m += 256) {
        float2 p = make_float2(xb[m * D_ + 0], xb[m * D_ + 1]);
        pts[m] = p;
        sqs[m] = __fadd_rn(__fmul_rn(p.x, p.x), __fmul_rn(p.y, p.y));
    }
    __syncthreads();

    const int q = qbase + t;
    const float2 qp = pts[q];
    const float sqn = sqs[q];

    for (int k = 0; k < K_; k++) {
        float2 p = pts[k];
        float dot = __fmaf_rn(qp.y, p.y, __fmul_rn(qp.x, p.x));
        bdL[k][t] = __fsub_rn(__fadd_rn(sqn, sqs[k]), __fmul_rn(2.f, dot));
        biL[k][t] = k;
    }

    float wd; int wslot;
    {
        wd = bdL[0][t]; int wi = biL[0][t]; wslot = 0;
        for (int j = 1; j < K_; j++) {
            float bdj = bdL[j][t]; int bij = biL[j][t];
            bool g = (bdj > wd) || (bdj == wd && bij > wi);
            if (g) { wd = bdj; wi = bij; wslot = j; }
        }
    }

    for (int m = K_; m < N_; m++) {
        float2 p = pts[m];
        float dot = __fmaf_rn(qp.y, p.y, __fmul_rn(qp.x, p.x));
        float d = __fsub_rn(__fadd_rn(sqn, sqs[m]), __fmul_rn(2.f, dot));
        if (d < wd) {   // strict: boundary tie keeps incumbent -> top_k semantics
            bdL[wslot][t] = d;          // == r3's "for j: if (j==wslot) write"
            biL[wslot][t] = m;
            // rescan for new worst (r3-exact)
            wd = bdL[0][t]; int wi = biL[0][t]; wslot = 0;
            for (int j = 1; j < K_; j++) {
                float bdj = bdL[j][t]; int bij = biL[j][t];
                bool g = (bdj > wd) || (bdj == wd && bij > wi);
                if (g) { wd = bdj; wi = bij; wslot = j; }
            }
        }
    }

    int* op = idx + ((size_t)b * N_ + q) * K_;
    for (int k = 0; k < K_; k++) op[k] = biL[k][t];
}

// ---------------- K3: gather-max over neighbors + epilogue ------------------
__global__ __launch_bounds__(256) void pool_kernel(const float* __restrict__ x,
                                                   const float* __restrict__ bias,
                                                   const float* __restrict__ Y,
                                                   const int* __restrict__ idx,
                                                   float* __restrict__ out) {
    const int t = threadIdx.x;
    const int w = t >> 6, f = t & 63;
    const int p = blockIdx.x * 4 + w;       // global point id
    const int b = p >> 11;                  // p / N_
    const size_t pb = (size_t)p;

    const float yn = Y[pb * F_ + f];
    const int* ip = idx + pb * K_;
    float M = -INFINITY;
#pragma unroll
    for (int k = 0; k < K_; k++) {
        int m = ip[k];
        float ym = Y[((size_t)b * N_ + m) * F_ + f];
        M = fmaxf(M, ym);
    }
    float pooled = fmaxf(yn, M - yn) + bias[f];
    out[pb * OUTD + f] = pooled;
    if (f < D_) out[pb * OUTD + F_ + f] = x[pb * D_ + f];
}

extern "C" void kernel_launch(void* const* d_in, const int* in_sizes, int n_in,
                              void* d_out, int out_size, void* d_ws, size_t ws_size,
                              hipStream_t stream) {
    const float* x    = (const float*)d_in[0];
    const float* W    = (const float*)d_in[1];
    const float* bias = (const float*)d_in[2];
    float* out = (float*)d_out;

    float* Y  = (float*)d_ws;                                        // 16.78 MB
    int*  idx = (int*)((char*)d_ws + (size_t)B_ * N_ * F_ * 4);      // +4.19 MB

    proj_kernel<<<B_ * N_ / 4, 256, 0, stream>>>(x, W, Y);
    knn_kernel <<<B_ * (N_ / 256), 256, 0, stream>>>(x, idx);
    pool_kernel<<<B_ * N_ / 4, 256, 0, stream>>>(x, bias, Y, idx, out);
}

// Round 7
// 456.449 us; speedup vs baseline: 4.1781x; 4.1781x over previous
//
#include <hip/hip_runtime.h>

// EdgeConv: B=32, N=2048, D=16, PCD=2, K_NN=16, FILTERS=64
// out[b,n,0:64]  = max(y_n, max_k y_{nn_k} - y_n) + b   where y = x@W (linearity)
// out[b,n,64:80] = x[b,n,:]
//
// KNN distance arithmetic + staging are ROUND-6 VERBATIM (verified passing):
//   staging: float2 pts + separate sqs, scalar global loads
//   sq  = fl(fl(x*x) + fl(y*y))          (no FMA)
//   dot = fma(y_n, y_m, fl(x_n*x_m))     (contracted k-loop)
//   d   = fl(fl(sq_n+sq_m) - fl(2*dot))
// Selection rebuilt as 2 passes exploiting set-invariance of the max-pool:
//  P1: branchless values-only sorted-16 register network (pair merge:
//      key[j] = min3(key[j], max(key[j-1],y0), max(key[j-2],y1))) -> T = exact
//      16th-smallest distance. No divergence, no LDS top-k state (r6's LDS
//      slots: VALUBusy 10.8%, 2143 cyc/iter; r3's scratch spill: 1494).
//  P2: emit set {d < T} (front-growing) + first (16-c1) ties d==T
//      (back-growing, guard s>=c1) == top_k's lower-index-wins set exactly.
//      Pass-2 d is a bitwise-identical recompute of pass-1 d.

#define B_  32
#define N_  2048
#define D_  16
#define F_  64
#define K_  16
#define OUTD (F_ + D_)   // 80

// ---------------- K1: Y = X * W  (bias folded into pool kernel) -------------
__global__ __launch_bounds__(256) void proj_kernel(const float* __restrict__ x,
                                                   const float* __restrict__ W,
                                                   float* __restrict__ Y) {
    __shared__ float Ws[D_ * F_];     // 4 KB
    __shared__ float xs[4][D_];
    const int t = threadIdx.x;
    for (int i = t; i < D_ * F_; i += 256) Ws[i] = W[i];
    const int p0 = blockIdx.x * 4;
    if (t < 4 * D_) {
        int pw = t / D_, d = t % D_;
        xs[pw][d] = x[(size_t)(p0 + pw) * D_ + d];
    }
    __syncthreads();
    const int w = t >> 6, f = t & 63;
    float acc = 0.f;
#pragma unroll
    for (int d = 0; d < D_; d++) acc = fmaf(xs[w][d], Ws[d * F_ + f], acc);
    Y[(size_t)(p0 + w) * F_ + f] = acc;
}

// ---------------- K2: exact 16-NN per point ---------------------------------
__global__ __launch_bounds__(256) void knn_kernel(const float* __restrict__ x,
                                                  int* __restrict__ idx) {
    __shared__ float2 pts[N_];        // 16 KB   (r6-verbatim staging)
    __shared__ float  sqs[N_];        // 8 KB
    const int b = blockIdx.x >> 3;          // 8 blocks per batch
    const int qbase = (blockIdx.x & 7) * 256;
    const int t = threadIdx.x;
    const float* xb = x + (size_t)b * N_ * D_;
    for (int m = t; m < N_; m += 256) {
        float2 p = make_float2(xb[m * D_ + 0], xb[m * D_ + 1]);
        pts[m] = p;
        sqs[m] = __fadd_rn(__fmul_rn(p.x, p.x), __fmul_rn(p.y, p.y));
    }
    __syncthreads();

    const int q = qbase + t;
    const float2 qp = pts[q];
    const float sqn = sqs[q];

    // ---- pass 1: branchless pair-merge network; key[] = 16 smallest values
    float key[K_];
#pragma unroll
    for (int j = 0; j < K_; j++) key[j] = INFINITY;

#pragma unroll 2
    for (int m = 0; m < N_; m += 2) {
        float2 pa = pts[m];     float sa = sqs[m];
        float2 pb = pts[m + 1]; float sb = sqs[m + 1];
        float dota = __fmaf_rn(qp.y, pa.y, __fmul_rn(qp.x, pa.x));
        float da   = __fsub_rn(__fadd_rn(sqn, sa), __fmul_rn(2.f, dota));
        float dotb = __fmaf_rn(qp.y, pb.y, __fmul_rn(qp.x, pb.x));
        float db   = __fsub_rn(__fadd_rn(sqn, sb), __fmul_rn(2.f, dotb));
        float y0 = fminf(da, db), y1 = fmaxf(da, db);
        // merge sorted pair {y0<=y1} into ascending key[0..15], drop 2 largest
#pragma unroll
        for (int j = K_ - 1; j >= 2; j--)
            key[j] = fminf(fminf(key[j], fmaxf(key[j - 1], y0)),
                           fmaxf(key[j - 2], y1));
        key[1] = fminf(fminf(key[1], fmaxf(key[0], y0)), y1);
        key[0] = fminf(key[0], y0);
    }
    const float T = key[K_ - 1];      // exact 16th-smallest distance

    // ---- pass 2: emit top_k's set. front: d<T at slots c1++ ; back: first
    // (16-c1) ties d==T at slots 15-tt (guard s>=c1; later front writes may
    // correctly overwrite dead ties). #{d<T} <= 15 and #ties >= 16-c1 by
    // definition of T, so exactly slots 0..15 are covered.
    int c1 = 0, tt = 0;
    int* op = idx + ((size_t)b * N_ + q) * K_;
    for (int m = 0; m < N_; m++) {
        float2 p = pts[m];
        float dot = __fmaf_rn(qp.y, p.y, __fmul_rn(qp.x, p.x));
        float d   = __fsub_rn(__fadd_rn(sqn, sqs[m]), __fmul_rn(2.f, dot));
        if (d < T) {
            op[c1++] = m;
        } else if (d == T) {
            int s = (K_ - 1) - tt;
            if (s >= c1) op[s] = m;
            tt++;
        }
    }
}

// ---------------- K3: gather-max over neighbors + epilogue ------------------
__global__ __launch_bounds__(256) void pool_kernel(const float* __restrict__ x,
                                                   const float* __restrict__ bias,
                                                   const float* __restrict__ Y,
                                                   const int* __restrict__ idx,
                                                   float* __restrict__ out) {
    const int t = threadIdx.x;
    const int w = t >> 6, f = t & 63;
    const int p = blockIdx.x * 4 + w;       // global point id
    const int b = p >> 11;                  // p / N_
    const size_t pb = (size_t)p;

    const float yn = Y[pb * F_ + f];
    const int* ip = idx + pb * K_;
    float M = -INFINITY;
#pragma unroll
    for (int k = 0; k < K_; k++) {
        int m = ip[k];
        float ym = Y[((size_t)b * N_ + m) * F_ + f];
        M = fmaxf(M, ym);
    }
    float pooled = fmaxf(yn, M - yn) + bias[f];
    out[pb * OUTD + f] = pooled;
    if (f < D_) out[pb * OUTD + F_ + f] = x[pb * D_ + f];
}

extern "C" void kernel_launch(void* const* d_in, const int* in_sizes, int n_in,
                              void* d_out, int out_size, void* d_ws, size_t ws_size,
                              hipStream_t stream) {
    const float* x    = (const float*)d_in[0];
    const float* W    = (const float*)d_in[1];
    const float* bias = (const float*)d_in[2];
    float* out = (float*)d_out;

    float* Y  = (float*)d_ws;                                        // 16.78 MB
    int*  idx = (int*)((char*)d_ws + (size_t)B_ * N_ * F_ * 4);      // +4.19 MB

    proj_kernel<<<B_ * N_ / 4, 256, 0, stream>>>(x, W, Y);
    knn_kernel <<<B_ * (N_ / 256), 256, 0, stream>>>(x, idx);
    pool_kernel<<<B_ * N_ / 4, 256, 0, stream>>>(x, bias, Y, idx, out);
}

// Round 8
// 293.844 us; speedup vs baseline: 6.4901x; 1.5534x over previous
//
#include <hip/hip_runtime.h>

// EdgeConv: B=32, N=2048, D=16, PCD=2, K_NN=16, FILTERS=64
// out[b,n,0:64]  = max(y_n, max_k y_{nn_k} - y_n) + b   where y = x@W (linearity)
// out[b,n,64:80] = x[b,n,:]
//
// KNN distance arithmetic + staging are R7-VERBATIM (verified passing):
//   staging: float2 pts + separate sqs, scalar global loads
//   sq  = fl(fl(x*x) + fl(y*y))   dot = fma(y_n,y_m, fl(x_n*x_m))
//   d   = fl(fl(sq_n+sq_m) - fl(2*dot))
// R8 change: 4-way candidate split per query for occupancy (r7: 1 wave/SIMD,
// VALUBusy 39%, 60% latency-idle). Each wave runs r7's pair-merge network on
// 512 candidates -> partial sorted-16; wave 0 merges 4 lists -> exact global
// T; pass 2 splits 4-way, strict d<T via LDS-atomic slots (set-invariant
// order), ties d==T consumed split-ascending, index-ascending == top_k's
// lower-index-wins set exactly (need<=16 so per-split cap 16 is sufficient).

#define B_  32
#define N_  2048
#define D_  16
#define F_  64
#define K_  16
#define OUTD (F_ + D_)   // 80
#define NQ  64           // queries per block
#define NS  4            // candidate splits (= waves per block)
#define SPLIT (N_ / NS)  // 512

// ---------------- K1: Y = X * W  (bias folded into pool kernel) -------------
__global__ __launch_bounds__(256) void proj_kernel(const float* __restrict__ x,
                                                   const float* __restrict__ W,
                                                   float* __restrict__ Y) {
    __shared__ float Ws[D_ * F_];     // 4 KB
    __shared__ float xs[4][D_];
    const int t = threadIdx.x;
    for (int i = t; i < D_ * F_; i += 256) Ws[i] = W[i];
    const int p0 = blockIdx.x * 4;
    if (t < 4 * D_) {
        int pw = t / D_, d = t % D_;
        xs[pw][d] = x[(size_t)(p0 + pw) * D_ + d];
    }
    __syncthreads();
    const int w = t >> 6, f = t & 63;
    float acc = 0.f;
#pragma unroll
    for (int d = 0; d < D_; d++) acc = fmaf(xs[w][d], Ws[d * F_ + f], acc);
    Y[(size_t)(p0 + w) * F_ + f] = acc;
}

// ---------------- K2: exact 16-NN per point, 4-way split --------------------
__global__ __launch_bounds__(256) void knn_kernel(const float* __restrict__ x,
                                                  int* __restrict__ idx) {
    __shared__ float2 pts[N_];                     // 16 KB (r7-verbatim)
    __shared__ float  sqs[N_];                     // 8 KB
    __shared__ float  arr[NS - 1][NQ * 17];        // 13 KB: sorted-16 of s=1..3 (pad 17)
    __shared__ float  Tq[NQ];
    __shared__ int    cnt[NQ];
    __shared__ unsigned short tiebuf[NS][NQ][K_];  // 8 KB
    __shared__ int    tiecnt[NS][NQ];              // 1 KB

    const int b = blockIdx.x >> 5;                 // 32 blocks per batch
    const int qbase = (blockIdx.x & 31) * NQ;
    const int t = threadIdx.x;
    const int s = t >> 6;                          // wave id = split id
    const int qi = t & 63;
    const int q = qbase + qi;

    const float* xb = x + (size_t)b * N_ * D_;
    for (int m = t; m < N_; m += 256) {
        float2 p = make_float2(xb[m * D_ + 0], xb[m * D_ + 1]);
        pts[m] = p;
        sqs[m] = __fadd_rn(__fmul_rn(p.x, p.x), __fmul_rn(p.y, p.y));
    }
    if (t < NQ) cnt[t] = 0;
    __syncthreads();

    const float2 qp = pts[q];
    const float sqn = sqs[q];

    // ---- pass 1 (per split): r7-verbatim pair-merge network over 512 cands
    float key[K_];
#pragma unroll
    for (int j = 0; j < K_; j++) key[j] = INFINITY;

    const int m0 = s * SPLIT, m1 = m0 + SPLIT;
#pragma unroll 2
    for (int m = m0; m < m1; m += 2) {
        float2 pa = pts[m];     float sa = sqs[m];
        float2 pb = pts[m + 1]; float sb = sqs[m + 1];
        float dota = __fmaf_rn(qp.y, pa.y, __fmul_rn(qp.x, pa.x));
        float da   = __fsub_rn(__fadd_rn(sqn, sa), __fmul_rn(2.f, dota));
        float dotb = __fmaf_rn(qp.y, pb.y, __fmul_rn(qp.x, pb.x));
        float db   = __fsub_rn(__fadd_rn(sqn, sb), __fmul_rn(2.f, dotb));
        float y0 = fminf(da, db), y1 = fmaxf(da, db);
#pragma unroll
        for (int j = K_ - 1; j >= 2; j--)
            key[j] = fminf(fminf(key[j], fmaxf(key[j - 1], y0)),
                           fmaxf(key[j - 2], y1));
        key[1] = fminf(fminf(key[1], fmaxf(key[0], y0)), y1);
        key[0] = fminf(key[0], y0);
    }

    if (s > 0) {
#pragma unroll
        for (int j = 0; j < K_; j++) arr[s - 1][qi * 17 + j] = key[j];
    }
    __syncthreads();

    // ---- merge (wave 0): stream splits 1..3 (already sorted -> pairs ordered)
    if (s == 0) {
        for (int ss = 0; ss < NS - 1; ss++) {
#pragma unroll
            for (int j = 0; j < K_; j += 2) {
                float y0 = arr[ss][qi * 17 + j];
                float y1 = arr[ss][qi * 17 + j + 1];   // y0 <= y1 by construction
#pragma unroll
                for (int jj = K_ - 1; jj >= 2; jj--)
                    key[jj] = fminf(fminf(key[jj], fmaxf(key[jj - 1], y0)),
                                    fmaxf(key[jj - 2], y1));
                key[1] = fminf(fminf(key[1], fmaxf(key[0], y0)), y1);
                key[0] = fminf(key[0], y0);
            }
        }
        Tq[qi] = key[K_ - 1];     // exact global 16th-smallest distance
    }
    __syncthreads();

    // ---- pass 2 (all splits): emit strict d<T via atomic slots; record ties
    const float T = Tq[qi];
    int* op = idx + ((size_t)b * N_ + q) * K_;
    int tc = 0;
    for (int m = m0; m < m1; m++) {
        float2 p = pts[m];
        float dot = __fmaf_rn(qp.y, p.y, __fmul_rn(qp.x, p.x));
        float d   = __fsub_rn(__fadd_rn(sqn, sqs[m]), __fmul_rn(2.f, dot));
        if (d < T) {
            int slot = atomicAdd(&cnt[qi], 1);     // #{d<T} <= 15, slots unique
            op[slot] = m;
        } else if (d == T) {
            if (tc < K_) tiebuf[s][qi][tc] = (unsigned short)m;
            tc++;
        }
    }
    tiecnt[s][qi] = (tc < K_) ? tc : K_;
    __syncthreads();

    // ---- tie fill (wave 0): first (16-c1) ties, split-asc then index-asc
    if (s == 0) {
        int c1 = cnt[qi];
        int w = c1;
        int need = K_ - c1;                        // >= 1 always
        for (int ss = 0; ss < NS && need > 0; ss++) {
            int nn = tiecnt[ss][qi];
            for (int j = 0; j < nn && need > 0; j++) {
                op[w++] = (int)tiebuf[ss][qi][j];
                need--;
            }
        }
    }
}

// ---------------- K3: gather-max over neighbors + epilogue ------------------
__global__ __launch_bounds__(256) void pool_kernel(const float* __restrict__ x,
                                                   const float* __restrict__ bias,
                                                   const float* __restrict__ Y,
                                                   const int* __restrict__ idx,
                                                   float* __restrict__ out) {
    const int t = threadIdx.x;
    const int w = t >> 6, f = t & 63;
    const int p = blockIdx.x * 4 + w;       // global point id
    const int b = p >> 11;                  // p / N_
    const size_t pb = (size_t)p;

    const float yn = Y[pb * F_ + f];
    const int* ip = idx + pb * K_;
    float M = -INFINITY;
#pragma unroll
    for (int k = 0; k < K_; k++) {
        int m = ip[k];
        float ym = Y[((size_t)b * N_ + m) * F_ + f];
        M = fmaxf(M, ym);
    }
    float pooled = fmaxf(yn, M - yn) + bias[f];
    out[pb * OUTD + f] = pooled;
    if (f < D_) out[pb * OUTD + F_ + f] = x[pb * D_ + f];
}

extern "C" void kernel_launch(void* const* d_in, const int* in_sizes, int n_in,
                              void* d_out, int out_size, void* d_ws, size_t ws_size,
                              hipStream_t stream) {
    const float* x    = (const float*)d_in[0];
    const float* W    = (const float*)d_in[1];
    const float* bias = (const float*)d_in[2];
    float* out = (float*)d_out;

    float* Y  = (float*)d_ws;                                        // 16.78 MB
    int*  idx = (int*)((char*)d_ws + (size_t)B_ * N_ * F_ * 4);      // +4.19 MB

    proj_kernel<<<B_ * N_ / 4, 256, 0, stream>>>(x, W, Y);
    knn_kernel <<<B_ * (N_ / NQ), 256, 0, stream>>>(x, idx);
    pool_kernel<<<B_ * N_ / 4, 256, 0, stream>>>(x, bias, Y, idx, out);
}

// Round 9
// 289.986 us; speedup vs baseline: 6.5765x; 1.0133x over previous
//
#include <hip/hip_runtime.h>

// EdgeConv: B=32, N=2048, D=16, PCD=2, K_NN=16, FILTERS=64
// out[b,n,0:64]  = max(y_n, max_k y_{nn_k} - y_n) + b   where y = x@W (linearity)
// out[b,n,64:80] = x[b,n,:]
//
// KNN = R8-VERBATIM semantics (verified passing, absmax 0.03125):
//   staging: float2 pts + separate sqs, scalar global loads
//   sq  = fl(fl(x*x) + fl(y*y))   dot = fma(y_n,y_m, fl(x_n*x_m))
//   d   = fl(fl(sq_n+sq_m) - fl(2*dot))
//   P1 branchless pair-merge sorted-16 per 512-split; wave0 merges -> exact T;
//   P2 atomic-slot emit d<T + split-asc tie fill == top_k lower-index-wins.
// R9 delta (perf only, no semantics):
//   - LDS overlay: arr (live barriers 2-3) and tiebuf (live after barrier 3)
//     share storage -> 47.6K -> 39.2K -> 4 blocks/CU (was 3). r8: Occ 27.6%,
//     VALUBusy 69%, 31% latency-idle at 2.2 waves/SIMD.
//   - proj/pool: 16 points/block (grid 16384->4096), 4x fewer W/bias reloads.

#define B_  32
#define N_  2048
#define D_  16
#define F_  64
#define K_  16
#define OUTD (F_ + D_)   // 80
#define NQ  64           // queries per block
#define NS  4            // candidate splits (= waves per block)
#define SPLIT (N_ / NS)  // 512

// ---------------- K1: Y = X * W  (bias folded into pool kernel) -------------
__global__ __launch_bounds__(256) void proj_kernel(const float* __restrict__ x,
                                                   const float* __restrict__ W,
                                                   float* __restrict__ Y) {
    __shared__ float Ws[D_ * F_];     // 4 KB
    __shared__ float xs[16][D_];      // 1 KB
    const int t = threadIdx.x;
    for (int i = t; i < D_ * F_; i += 256) Ws[i] = W[i];
    const int p0 = blockIdx.x * 16;
    // xs flat load: address p0*16 + t  -> perfectly coalesced 1 KB
    ((float*)xs)[t] = x[(size_t)p0 * D_ + t];
    __syncthreads();
    const int w = t >> 6, f = t & 63;
#pragma unroll
    for (int i = 0; i < 4; i++) {
        const int pw = w * 4 + i;
        float acc = 0.f;
#pragma unroll
        for (int d = 0; d < D_; d++) acc = fmaf(xs[pw][d], Ws[d * F_ + f], acc);
        Y[(size_t)(p0 + pw) * F_ + f] = acc;
    }
}

// ---------------- K2: exact 16-NN per point, 4-way split --------------------
__global__ __launch_bounds__(256, 4) void knn_kernel(const float* __restrict__ x,
                                                     int* __restrict__ idx) {
    __shared__ float2 pts[N_];                     // 16 KB (r8-verbatim)
    __shared__ float  sqs[N_];                     // 8 KB
    // overlay: arr lives [barrier2, barrier3); tiebuf lives [barrier3, end)
    __shared__ float  arr_raw[NS - 1][NQ * 17];    // 12.75 KB
    __shared__ float  Tq[NQ];
    __shared__ int    cnt[NQ];
    __shared__ int    tiecnt[NS][NQ];              // 1 KB
    unsigned short (*tiebuf)[NQ][K_] =
        (unsigned short (*)[NQ][K_])&arr_raw[0][0];   // 8 KB <= 12.75 KB

    const int b = blockIdx.x >> 5;                 // 32 blocks per batch
    const int qbase = (blockIdx.x & 31) * NQ;
    const int t = threadIdx.x;
    const int s = t >> 6;                          // wave id = split id
    const int qi = t & 63;
    const int q = qbase + qi;

    const float* xb = x + (size_t)b * N_ * D_;
    for (int m = t; m < N_; m += 256) {
        float2 p = make_float2(xb[m * D_ + 0], xb[m * D_ + 1]);
        pts[m] = p;
        sqs[m] = __fadd_rn(__fmul_rn(p.x, p.x), __fmul_rn(p.y, p.y));
    }
    if (t < NQ) cnt[t] = 0;
    __syncthreads();                               // barrier 1

    const float2 qp = pts[q];
    const float sqn = sqs[q];

    // ---- pass 1 (per split): branchless pair-merge network over 512 cands
    float key[K_];
#pragma unroll
    for (int j = 0; j < K_; j++) key[j] = INFINITY;

    const int m0 = s * SPLIT, m1 = m0 + SPLIT;
#pragma unroll 2
    for (int m = m0; m < m1; m += 2) {
        float2 pa = pts[m];     float sa = sqs[m];
        float2 pb = pts[m + 1]; float sb = sqs[m + 1];
        float dota = __fmaf_rn(qp.y, pa.y, __fmul_rn(qp.x, pa.x));
        float da   = __fsub_rn(__fadd_rn(sqn, sa), __fmul_rn(2.f, dota));
        float dotb = __fmaf_rn(qp.y, pb.y, __fmul_rn(qp.x, pb.x));
        float db   = __fsub_rn(__fadd_rn(sqn, sb), __fmul_rn(2.f, dotb));
        float y0 = fminf(da, db), y1 = fmaxf(da, db);
#pragma unroll
        for (int j = K_ - 1; j >= 2; j--)
            key[j] = fminf(fminf(key[j], fmaxf(key[j - 1], y0)),
                           fmaxf(key[j - 2], y1));
        key[1] = fminf(fminf(key[1], fmaxf(key[0], y0)), y1);
        key[0] = fminf(key[0], y0);
    }

    if (s > 0) {
#pragma unroll
        for (int j = 0; j < K_; j++) arr_raw[s - 1][qi * 17 + j] = key[j];
    }
    __syncthreads();                               // barrier 2

    // ---- merge (wave 0): stream splits 1..3 (sorted -> pairs ordered)
    if (s == 0) {
        for (int ss = 0; ss < NS - 1; ss++) {
#pragma unroll
            for (int j = 0; j < K_; j += 2) {
                float y0 = arr_raw[ss][qi * 17 + j];
                float y1 = arr_raw[ss][qi * 17 + j + 1];   // y0 <= y1
#pragma unroll
                for (int jj = K_ - 1; jj >= 2; jj--)
                    key[jj] = fminf(fminf(key[jj], fmaxf(key[jj - 1], y0)),
                                    fmaxf(key[jj - 2], y1));
                key[1] = fminf(fminf(key[1], fmaxf(key[0], y0)), y1);
                key[0] = fminf(key[0], y0);
            }
        }
        Tq[qi] = key[K_ - 1];     // exact global 16th-smallest distance
    }
    __syncthreads();                               // barrier 3 (arr dead now)

    // ---- pass 2 (all splits): emit strict d<T via atomic slots; record ties
    const float T = Tq[qi];
    int* op = idx + ((size_t)b * N_ + q) * K_;
    int tc = 0;
    for (int m = m0; m < m1; m++) {
        float2 p = pts[m];
        float dot = __fmaf_rn(qp.y, p.y, __fmul_rn(qp.x, p.x));
        float d   = __fsub_rn(__fadd_rn(sqn, sqs[m]), __fmul_rn(2.f, dot));
        if (d < T) {
            int slot = atomicAdd(&cnt[qi], 1);     // #{d<T} <= 15, slots unique
            op[slot] = m;
        } else if (d == T) {
            if (tc < K_) tiebuf[s][qi][tc] = (unsigned short)m;
            tc++;
        }
    }
    tiecnt[s][qi] = (tc < K_) ? tc : K_;
    __syncthreads();                               // barrier 4

    // ---- tie fill (wave 0): first (16-c1) ties, split-asc then index-asc
    if (s == 0) {
        int c1 = cnt[qi];
        int w = c1;
        int need = K_ - c1;                        // >= 1 always
        for (int ss = 0; ss < NS && need > 0; ss++) {
            int nn = tiecnt[ss][qi];
            for (int j = 0; j < nn && need > 0; j++) {
                op[w++] = (int)tiebuf[ss][qi][j];
                need--;
            }
        }
    }
}

// ---------------- K3: gather-max over neighbors + epilogue ------------------
__global__ __launch_bounds__(256) void pool_kernel(const float* __restrict__ x,
                                                   const float* __restrict__ bias,
                                                   const float* __restrict__ Y,
                                                   const int* __restrict__ idx,
                                                   float* __restrict__ out) {
    const int t = threadIdx.x;
    const int w = t >> 6, f = t & 63;
    const float bf = bias[f];
#pragma unroll
    for (int i = 0; i < 4; i++) {
        const int p = blockIdx.x * 16 + w * 4 + i;   // global point id
        const int b = p >> 11;                       // p / N_
        const size_t pb = (size_t)p;

        const float yn = Y[pb * F_ + f];
        const int* ip = idx + pb * K_;
        float M = -INFINITY;
#pragma unroll
        for (int k = 0; k < K_; k++) {
            int m = ip[k];
            float ym = Y[((size_t)b * N_ + m) * F_ + f];
            M = fmaxf(M, ym);
        }
        float pooled = fmaxf(yn, M - yn) + bf;
        out[pb * OUTD + f] = pooled;
        if (f < D_) out[pb * OUTD + F_ + f] = x[pb * D_ + f];
    }
}

extern "C" void kernel_launch(void* const* d_in, const int* in_sizes, int n_in,
                              void* d_out, int out_size, void* d_ws, size_t ws_size,
                              hipStream_t stream) {
    const float* x    = (const float*)d_in[0];
    const float* W    = (const float*)d_in[1];
    const float* bias = (const float*)d_in[2];
    float* out = (float*)d_out;

    float* Y  = (float*)d_ws;                                        // 16.78 MB
    int*  idx = (int*)((char*)d_ws + (size_t)B_ * N_ * F_ * 4);      // +4.19 MB

    proj_kernel<<<B_ * N_ / 16, 256, 0, stream>>>(x, W, Y);
    knn_kernel <<<B_ * (N_ / NQ), 256, 0, stream>>>(x, idx);
    pool_kernel<<<B_ * N_ / 16, 256, 0, stream>>>(x, bias, Y, idx, out);
}

// Round 10
// 259.356 us; speedup vs baseline: 7.3532x; 1.1181x over previous
//
#include <hip/hip_runtime.h>

// EdgeConv: B=32, N=2048, D=16, PCD=2, K_NN=16, FILTERS=64
// out[b,n,0:64]  = max(y_n, max_k y_{nn_k} - y_n) + b   where y = x@W (linearity)
// out[b,n,64:80] = x[b,n,:]
//
// KNN selection = R9-VERBATIM semantics (verified passing, absmax 0.03125):
//   staging: float2 pts + separate sqs, scalar global loads
//   sq  = fl(fl(x*x) + fl(y*y))   dot = fma(y_n,y_m, fl(x_n*x_m))
//   d   = fl(fl(sq_n+sq_m) - fl(2*dot))
//   P1 branchless pair-merge sorted-16 per 512-split; wave0 merges -> exact T;
//   P2 atomic-slot emit d<T + split-asc tie fill == top_k lower-index-wins.
// R10 delta (perf only, selection/numerics untouched):
//   - pool FUSED into knn tail: idx lives in LDS (overlaid on dead tiebuf
//     region), Y gathered per neighbor row (coalesced, L2-hot), out written
//     directly. Removes pool kernel + 8 MB idx round-trip.
//   - pass-1 unroll 4 / pass-2 unroll 2 (same iteration order, same bits).

#define B_  32
#define N_  2048
#define D_  16
#define F_  64
#define K_  16
#define OUTD (F_ + D_)   // 80
#define NQ  64           // queries per block
#define NS  4            // candidate splits (= waves per block)
#define SPLIT (N_ / NS)  // 512

// ---------------- K1: Y = X * W  (bias folded into fused kernel) ------------
__global__ __launch_bounds__(256) void proj_kernel(const float* __restrict__ x,
                                                   const float* __restrict__ W,
                                                   float* __restrict__ Y) {
    __shared__ float Ws[D_ * F_];     // 4 KB
    __shared__ float xs[16][D_];      // 1 KB
    const int t = threadIdx.x;
    for (int i = t; i < D_ * F_; i += 256) Ws[i] = W[i];
    const int p0 = blockIdx.x * 16;
    ((float*)xs)[t] = x[(size_t)p0 * D_ + t];   // coalesced 1 KB
    __syncthreads();
    const int w = t >> 6, f = t & 63;
#pragma unroll
    for (int i = 0; i < 4; i++) {
        const int pw = w * 4 + i;
        float acc = 0.f;
#pragma unroll
        for (int d = 0; d < D_; d++) acc = fmaf(xs[pw][d], Ws[d * F_ + f], acc);
        Y[(size_t)(p0 + pw) * F_ + f] = acc;
    }
}

// ---------------- K2: exact 16-NN + fused conv-max-pool epilogue ------------
__global__ __launch_bounds__(256, 4) void knn_kernel(const float* __restrict__ x,
                                                     const float* __restrict__ bias,
                                                     const float* __restrict__ Y,
                                                     float* __restrict__ out) {
    __shared__ float2 pts[N_];                     // 16 KB (r9-verbatim)
    __shared__ float  sqs[N_];                     // 8 KB
    // overlay region (13056 B): arr lives [barrier2, barrier3);
    // tiebuf (8192 B @ +0) and idxL (4096 B @ +8192) live [barrier3, end)
    __shared__ float  arr_raw[NS - 1][NQ * 17];    // 12.75 KB
    __shared__ float  Tq[NQ];
    __shared__ int    cnt[NQ];
    __shared__ int    tiecnt[NS][NQ];              // 1 KB
    unsigned short (*tiebuf)[NQ][K_] =
        (unsigned short (*)[NQ][K_])&arr_raw[0][0];          // 8 KB
    int (*idxL)[K_] = (int (*)[K_])((char*)&arr_raw[0][0] + 8192);  // 4 KB

    const int b = blockIdx.x >> 5;                 // 32 blocks per batch
    const int qbase = (blockIdx.x & 31) * NQ;
    const int t = threadIdx.x;
    const int s = t >> 6;                          // wave id = split id
    const int qi = t & 63;
    const int q = qbase + qi;

    const float* xb = x + (size_t)b * N_ * D_;
    for (int m = t; m < N_; m += 256) {
        float2 p = make_float2(xb[m * D_ + 0], xb[m * D_ + 1]);
        pts[m] = p;
        sqs[m] = __fadd_rn(__fmul_rn(p.x, p.x), __fmul_rn(p.y, p.y));
    }
    if (t < NQ) cnt[t] = 0;
    __syncthreads();                               // barrier 1

    const float2 qp = pts[q];
    const float sqn = sqs[q];

    // ---- pass 1 (per split): branchless pair-merge network over 512 cands
    float key[K_];
#pragma unroll
    for (int j = 0; j < K_; j++) key[j] = INFINITY;

    const int m0 = s * SPLIT, m1 = m0 + SPLIT;
#pragma unroll 4
    for (int m = m0; m < m1; m += 2) {
        float2 pa = pts[m];     float sa = sqs[m];
        float2 pb = pts[m + 1]; float sb = sqs[m + 1];
        float dota = __fmaf_rn(qp.y, pa.y, __fmul_rn(qp.x, pa.x));
        float da   = __fsub_rn(__fadd_rn(sqn, sa), __fmul_rn(2.f, dota));
        float dotb = __fmaf_rn(qp.y, pb.y, __fmul_rn(qp.x, pb.x));
        float db   = __fsub_rn(__fadd_rn(sqn, sb), __fmul_rn(2.f, dotb));
        float y0 = fminf(da, db), y1 = fmaxf(da, db);
#pragma unroll
        for (int j = K_ - 1; j >= 2; j--)
            key[j] = fminf(fminf(key[j], fmaxf(key[j - 1], y0)),
                           fmaxf(key[j - 2], y1));
        key[1] = fminf(fminf(key[1], fmaxf(key[0], y0)), y1);
        key[0] = fminf(key[0], y0);
    }

    if (s > 0) {
#pragma unroll
        for (int j = 0; j < K_; j++) arr_raw[s - 1][qi * 17 + j] = key[j];
    }
    __syncthreads();                               // barrier 2

    // ---- merge (wave 0): stream splits 1..3 (sorted -> pairs ordered)
    if (s == 0) {
        for (int ss = 0; ss < NS - 1; ss++) {
#pragma unroll
            for (int j = 0; j < K_; j += 2) {
                float y0 = arr_raw[ss][qi * 17 + j];
                float y1 = arr_raw[ss][qi * 17 + j + 1];   // y0 <= y1
#pragma unroll
                for (int jj = K_ - 1; jj >= 2; jj--)
                    key[jj] = fminf(fminf(key[jj], fmaxf(key[jj - 1], y0)),
                                    fmaxf(key[jj - 2], y1));
                key[1] = fminf(fminf(key[1], fmaxf(key[0], y0)), y1);
                key[0] = fminf(key[0], y0);
            }
        }
        Tq[qi] = key[K_ - 1];     // exact global 16th-smallest distance
    }
    __syncthreads();                               // barrier 3 (arr dead now)

    // ---- pass 2 (all splits): emit strict d<T via atomic slots; record ties
    const float T = Tq[qi];
    int tc = 0;
#pragma unroll 2
    for (int m = m0; m < m1; m++) {
        float2 p = pts[m];
        float dot = __fmaf_rn(qp.y, p.y, __fmul_rn(qp.x, p.x));
        float d   = __fsub_rn(__fadd_rn(sqn, sqs[m]), __fmul_rn(2.f, dot));
        if (d < T) {
            int slot = atomicAdd(&cnt[qi], 1);     // #{d<T} <= 15, slots unique
            idxL[qi][slot] = m;
        } else if (d == T) {
            if (tc < K_) tiebuf[s][qi][tc] = (unsigned short)m;
            tc++;
        }
    }
    tiecnt[s][qi] = (tc < K_) ? tc : K_;
    __syncthreads();                               // barrier 4

    // ---- tie fill (wave 0): first (16-c1) ties, split-asc then index-asc
    if (s == 0) {
        int c1 = cnt[qi];
        int w = c1;
        int need = K_ - c1;                        // >= 1 always
        for (int ss = 0; ss < NS && need > 0; ss++) {
            int nn = tiecnt[ss][qi];
            for (int j = 0; j < nn && need > 0; j++) {
                idxL[qi][w++] = (int)tiebuf[ss][qi][j];
                need--;
            }
        }
    }
    __syncthreads();                               // barrier 5

    // ---- fused pool epilogue: wave s handles queries s*16 .. s*16+15
    const int f = qi;                              // lane = filter (64)
    const float bf = bias[f];
    const float* Yb = Y + (size_t)b * N_ * F_;
    for (int i = 0; i < 16; i++) {
        const int qq = s * 16 + i;                 // local query id
        const int gq = qbase + qq;                 // batch-local point id
        const float yn = Yb[(size_t)gq * F_ + f];
        float M = -INFINITY;
#pragma unroll
        for (int k = 0; k < K_; k++) {
            int m = idxL[qq][k];                   // wave-uniform -> broadcast
            M = fmaxf(M, Yb[(size_t)m * F_ + f]);  // coalesced 256B row
        }
        const size_t pb = (size_t)b * N_ + gq;
        out[pb * OUTD + f] = fmaxf(yn, M - yn) + bf;
        if (f < D_) out[pb * OUTD + F_ + f] = xb[(size_t)gq * D_ + f];
    }
}

extern "C" void kernel_launch(void* const* d_in, const int* in_sizes, int n_in,
                              void* d_out, int out_size, void* d_ws, size_t ws_size,
                              hipStream_t stream) {
    const float* x    = (const float*)d_in[0];
    const float* W    = (const float*)d_in[1];
    const float* bias = (const float*)d_in[2];
    float* out = (float*)d_out;

    float* Y = (float*)d_ws;                       // 16.78 MB scratch

    proj_kernel<<<B_ * N_ / 16, 256, 0, stream>>>(x, W, Y);
    knn_kernel <<<B_ * (N_ / NQ), 256, 0, stream>>>(x, bias, Y, out);
}